// Round 7
// baseline (3324.409 us; speedup 1.0000x reference)
//
#include <hip/hip_runtime.h>
#include <stdint.h>

// Problem constants (fixed by the reference): P=8192, L=64, H=128.
#define PCNT 8192
#define LROW 64
#define HDIM 128
#define XSTR 136                    // padded k-stride for x_lds and wt (16B aligned)
#define WBUF_ELEMS (128 * XSTR)     // one transposed weight buffer in ws, fp16
#define NPOLY 4                     // polylines per block (grid = PCNT/NPOLY = 2048)

typedef _Float16 f16;
typedef __attribute__((ext_vector_type(8))) _Float16 half8;
typedef __attribute__((ext_vector_type(4))) _Float16 half4v;
typedef __attribute__((ext_vector_type(2))) _Float16 half2v;
typedef __attribute__((ext_vector_type(4))) float f32x4;

#define MFMA16(A, B, C) __builtin_amdgcn_mfma_f32_16x16x32_f16((A), (B), (C), 0, 0, 0)

__device__ __forceinline__ half8 ldh8(const f16* p) {
  return *reinterpret_cast<const half8*>(p);
}

union PkU { uint32_t u; half2v h; };

__device__ __forceinline__ uint32_t pk2(float lo, float hi) {
  PkU a;
  a.h[0] = (f16)lo;
  a.h[1] = (f16)hi;
  return a.u;
}

__device__ __forceinline__ uint32_t pkmax(uint32_t a, uint32_t b) {
  uint32_t d;
  asm("v_pk_max_f16 %0, %1, %2" : "=v"(d) : "v"(a), "v"(b));
  return d;
}

// ---------------------------------------------------------------------------
// Prep: W1 (128x128), W2/W3 (256x128) fp32 row-major  ->  ws as 5 transposed
// fp16 buffers Wt[c][k] with padded stride XSTR:
//   buf0 = W1^T, buf1 = W2[:128]^T (Wa2), buf2 = W2[128:]^T (Wb2),
//   buf3 = W3[:128]^T (Wa3), buf4 = W3[128:]^T (Wb3)
// ---------------------------------------------------------------------------
__global__ void prep_weights(const float* __restrict__ W1,
                             const float* __restrict__ W2,
                             const float* __restrict__ W3,
                             f16* __restrict__ wt) {
  int idx = blockIdx.x * 256 + threadIdx.x;
  if (idx >= 5 * WBUF_ELEMS) return;
  int buf = idx / WBUF_ELEMS;
  int rem = idx - buf * WBUF_ELEMS;
  int c = rem / XSTR;      // output column 0..127
  int k = rem - c * XSTR;  // k index 0..135 (128..135 = pad)
  float v = 0.0f;
  if (k < 128) {
    const float* W = (buf == 0) ? W1 : (buf <= 2 ? W2 : W3);
    int krow = k + ((buf == 2 || buf == 4) ? 128 : 0);
    v = W[krow * 128 + c];
  }
  wt[idx] = (f16)v;
}

// stage input rows [0, 16*mtiles): fp32 -> fp16, b128 LDS writes
__device__ __forceinline__ void stage_x(f16* __restrict__ x_lds,
                                        const float* __restrict__ hp,
                                        int mtiles, int tid) {
  for (int it = 0; it < mtiles; ++it) {
    int e = (it * 256 + tid) * 8;
    int r = e >> 7, c = e & 127;
    float4 va = *reinterpret_cast<const float4*>(hp + e);
    float4 vb = *reinterpret_cast<const float4*>(hp + e + 4);
    half8 hv;
    hv[0] = (f16)va.x; hv[1] = (f16)va.y; hv[2] = (f16)va.z; hv[3] = (f16)va.w;
    hv[4] = (f16)vb.x; hv[5] = (f16)vb.y; hv[6] = (f16)vb.z; hv[7] = (f16)vb.w;
    *reinterpret_cast<half8*>(&x_lds[r * XSTR + c]) = hv;
  }
}

// ---------------------------------------------------------------------------
// Fused persistent kernel, transposed-D layout (see R3): grid 2048 = exactly
// 8 blocks/CU resident (LDS 19968B*8 <= 160KB, VGPR <= 64); each block does
// NPOLY=4 polylines sequentially -> zero dispatch churn. Per layer: wbf+pv
// seed the accumulators BEFORE the GEMM (R3's 56-VGPR spill-free ordering),
// one stats barrier, per-lane redundant mu/rstd. Next polyline's staging is
// AFTER the full epilogue (acc/pm dead -> no live-range blowup; x_lds idle
// since layer-2 stats barrier; top-of-loop barrier publishes it).
// ---------------------------------------------------------------------------
__global__ __launch_bounds__(256, 4)
void fused_subgraph(const float* __restrict__ hs,
                    const int* __restrict__ lens,
                    const f16* __restrict__ wt,
                    const float* __restrict__ b1, const float* __restrict__ g1, const float* __restrict__ be1,
                    const float* __restrict__ b2, const float* __restrict__ g2, const float* __restrict__ be2,
                    const float* __restrict__ b3, const float* __restrict__ g3, const float* __restrict__ be3,
                    float* __restrict__ out) {
  __shared__ __align__(16) f16 x_lds[LROW * XSTR];   // 17408 B
  __shared__ float2 stats_s[4][LROW];                // per-wave row partial (sum, sumsq)
  __shared__ __align__(16) f16 phib[HDIM];           // phi (masked col-max), fp16

  const int tid = threadIdx.x;
  const int w = tid >> 6;   // wave 0..3
  const int l = tid & 63;   // lane

  const int l15 = l & 15;
  const int lg = l >> 4;                    // lane group 0..3
  const int ko = lg * 8;                    // k offset within a 32-k tile
  const int cb0 = w * 32 + lg * 4;          // lane's col base, nt=0 (4 consecutive cols)
  const int cb1 = cb0 + 16;                 // nt=1
  const int wrow0 = (w * 32 + l15) * XSTR;        // weight-fragment row offsets
  const int wrow1 = (w * 32 + 16 + l15) * XSTR;

  const int pbase = blockIdx.x * NPOLY;

  // ---- stage first polyline ----
  int len = lens[pbase];
  len = (len < 1) ? 1 : (len > LROW ? LROW : len);
  int mtiles = (len + 15) >> 4;
  stage_x(x_lds, hs + (size_t)pbase * (LROW * HDIM), mtiles, tid);

  for (int i = 0; i < NPOLY; ++i) {
    __syncthreads();  // staged x visible; stats_s free for reuse

#pragma unroll
    for (int layer = 0; layer < 3; ++layer) {
      const float* gv  = (layer == 0) ? g1  : (layer == 1) ? g2  : g3;
      const float* bev = (layer == 0) ? be1 : (layer == 1) ? be2 : be3;
      const float* bv  = (layer == 0) ? b1  : (layer == 1) ? b2  : b3;
      const f16* wa = wt + (size_t)((layer == 0) ? 0 : (layer == 1) ? 1 : 3) * WBUF_ELEMS;

      // ---- pv tile: row-constant bias[c] + (phi @ Wb)[c]  (seeds the GEMM acc) ----
      f32x4 pva0, pva1;
      {
        const float4 bl0 = *reinterpret_cast<const float4*>(bv + cb0);
        const float4 bl1 = *reinterpret_cast<const float4*>(bv + cb1);
        pva0[0] = bl0.x; pva0[1] = bl0.y; pva0[2] = bl0.z; pva0[3] = bl0.w;
        pva1[0] = bl1.x; pva1[1] = bl1.y; pva1[2] = bl1.z; pva1[3] = bl1.w;
      }
      if (layer > 0) {
        const f16* wb = wt + (size_t)((layer == 1) ? 2 : 4) * WBUF_ELEMS;
#pragma unroll
        for (int kc = 0; kc < 4; ++kc) {
          half8 wb0 = ldh8(&wb[wrow0 + kc * 32 + ko]);
          half8 wb1 = ldh8(&wb[wrow1 + kc * 32 + ko]);
          half8 ph = ldh8(&phib[kc * 32 + ko]);   // same in all lanes -> row-const D
          pva0 = MFMA16(wb0, ph, pva0);
          pva1 = MFMA16(wb1, ph, pva1);
        }
      }

      // ---- GEMM: acc[mt] = pv + (x @ Wa)^T tile ----
      f32x4 acc[4][2];
#pragma unroll
      for (int mt = 0; mt < 4; ++mt) { acc[mt][0] = pva0; acc[mt][1] = pva1; }
#pragma unroll
      for (int kc = 0; kc < 4; ++kc) {
        half8 wa0 = ldh8(&wa[wrow0 + kc * 32 + ko]);
        half8 wa1 = ldh8(&wa[wrow1 + kc * 32 + ko]);
#pragma unroll
        for (int mt = 0; mt < 4; ++mt) {
          if (mt < mtiles) {
            half8 bx = ldh8(&x_lds[(mt * 16 + l15) * XSTR + kc * 32 + ko]);
            acc[mt][0] = MFMA16(wa0, bx, acc[mt][0]);
            acc[mt][1] = MFMA16(wa1, bx, acc[mt][1]);
          }
        }
      }

      // ---- LN stats: in-lane 8-col partial + xor16/xor32 -> wave partial ----
#pragma unroll
      for (int mt = 0; mt < 4; ++mt) {
        if (mt < mtiles) {
          const f32x4 a0 = acc[mt][0], a1 = acc[mt][1];
          float s = ((a0[0] + a0[1]) + (a0[2] + a0[3])) + ((a1[0] + a1[1]) + (a1[2] + a1[3]));
          float q = a0[0] * a0[0];
          q = fmaf(a0[1], a0[1], q); q = fmaf(a0[2], a0[2], q); q = fmaf(a0[3], a0[3], q);
          q = fmaf(a1[0], a1[0], q); q = fmaf(a1[1], a1[1], q);
          q = fmaf(a1[2], a1[2], q); q = fmaf(a1[3], a1[3], q);
          s += __shfl_xor(s, 16); q += __shfl_xor(q, 16);
          s += __shfl_xor(s, 32); q += __shfl_xor(q, 32);
          if (l < 16) stats_s[w][mt * 16 + l15] = make_float2(s, q);
        }
      }
      __syncthreads();

      // ---- epilogue: per-lane mu/rstd from the 4 wave partials (no barrier),
      //      normalize+relu, write x' (f16), masked packed row-max ----
      const float4 gg0 = *reinterpret_cast<const float4*>(gv + cb0);
      const float4 gg1 = *reinterpret_cast<const float4*>(gv + cb1);
      const float4 eb0 = *reinterpret_cast<const float4*>(bev + cb0);
      const float4 eb1 = *reinterpret_cast<const float4*>(bev + cb1);
      uint32_t pm[4] = {0u, 0u, 0u, 0u};  // packed f16x2 col maxes (relu => 0 is identity)
#pragma unroll
      for (int mt = 0; mt < 4; ++mt) {
        if (mt < mtiles) {
          const int row = mt * 16 + l15;
          float2 t0 = stats_s[0][row], t1 = stats_s[1][row];
          float2 t2 = stats_s[2][row], t3 = stats_s[3][row];
          float s = (t0.x + t1.x) + (t2.x + t3.x);
          float q = (t0.y + t1.y) + (t2.y + t3.y);
          float mu = s * (1.0f / 128.0f);
          float var = q * (1.0f / 128.0f) - mu * mu;
          float rs = rsqrtf(var + 1e-5f);
          const bool valid = row < len;
          float v0 = fmaxf((acc[mt][0][0] - mu) * rs * gg0.x + eb0.x, 0.0f);
          float v1 = fmaxf((acc[mt][0][1] - mu) * rs * gg0.y + eb0.y, 0.0f);
          float v2 = fmaxf((acc[mt][0][2] - mu) * rs * gg0.z + eb0.z, 0.0f);
          float v3 = fmaxf((acc[mt][0][3] - mu) * rs * gg0.w + eb0.w, 0.0f);
          float u0 = fmaxf((acc[mt][1][0] - mu) * rs * gg1.x + eb1.x, 0.0f);
          float u1 = fmaxf((acc[mt][1][1] - mu) * rs * gg1.y + eb1.y, 0.0f);
          float u2 = fmaxf((acc[mt][1][2] - mu) * rs * gg1.z + eb1.z, 0.0f);
          float u3 = fmaxf((acc[mt][1][3] - mu) * rs * gg1.w + eb1.w, 0.0f);
          if (layer < 2) {
            half4v h0; h0[0] = (f16)v0; h0[1] = (f16)v1; h0[2] = (f16)v2; h0[3] = (f16)v3;
            half4v h1; h1[0] = (f16)u0; h1[1] = (f16)u1; h1[2] = (f16)u2; h1[3] = (f16)u3;
            *reinterpret_cast<half4v*>(&x_lds[row * XSTR + cb0]) = h0;
            *reinterpret_cast<half4v*>(&x_lds[row * XSTR + cb1]) = h1;
          }
          pm[0] = pkmax(pm[0], pk2(valid ? v0 : 0.0f, valid ? v1 : 0.0f));
          pm[1] = pkmax(pm[1], pk2(valid ? v2 : 0.0f, valid ? v3 : 0.0f));
          pm[2] = pkmax(pm[2], pk2(valid ? u0 : 0.0f, valid ? u1 : 0.0f));
          pm[3] = pkmax(pm[3], pk2(valid ? u2 : 0.0f, valid ? u3 : 0.0f));
        }
      }
      // reduce over the 16 l15 lanes (rows) — packed f16 max, 4 levels
#pragma unroll
      for (int d = 1; d <= 8; d <<= 1) {
#pragma unroll
        for (int j = 0; j < 4; ++j)
          pm[j] = pkmax(pm[j], (uint32_t)__shfl_xor((int)pm[j], d));
      }

      if (layer < 2) {
        if (l15 == 0) {  // phi for next layer's pv (4 consecutive f16 per uint2)
          *reinterpret_cast<uint2*>(&phib[cb0]) = make_uint2(pm[0], pm[1]);
          *reinterpret_cast<uint2*>(&phib[cb1]) = make_uint2(pm[2], pm[3]);
        }
        __syncthreads();  // x' + phib ready for next layer
      } else {
        if (l15 == 0) {  // output = concat(phi3, phi3)
          PkU q0, q1, q2, q3;
          q0.u = pm[0]; q1.u = pm[1]; q2.u = pm[2]; q3.u = pm[3];
          float4 o0 = make_float4((float)q0.h[0], (float)q0.h[1], (float)q1.h[0], (float)q1.h[1]);
          float4 o1 = make_float4((float)q2.h[0], (float)q2.h[1], (float)q3.h[0], (float)q3.h[1]);
          float* op = out + (size_t)(pbase + i) * 256;
          *reinterpret_cast<float4*>(op + cb0) = o0;
          *reinterpret_cast<float4*>(op + cb1) = o1;
          *reinterpret_cast<float4*>(op + 128 + cb0) = o0;
          *reinterpret_cast<float4*>(op + 128 + cb1) = o1;
        }
      }
    }

    // ---- stage next polyline at the register-pressure minimum (acc/pm dead;
    //      x_lds idle since layer-2 stats barrier; published by top barrier) ----
    if (i + 1 < NPOLY) {
      const int np = pbase + i + 1;
      len = lens[np];
      len = (len < 1) ? 1 : (len > LROW ? LROW : len);
      mtiles = (len + 15) >> 4;
      stage_x(x_lds, hs + (size_t)np * (LROW * HDIM), mtiles, tid);
    }
  }
}

extern "C" void kernel_launch(void* const* d_in, const int* in_sizes, int n_in,
                              void* d_out, int out_size, void* d_ws, size_t ws_size,
                              hipStream_t stream) {
  const float* hs  = (const float*)d_in[0];
  const int* lens  = (const int*)d_in[1];
  const float* W1  = (const float*)d_in[2];
  const float* b1  = (const float*)d_in[3];
  const float* g1  = (const float*)d_in[4];
  const float* be1 = (const float*)d_in[5];
  const float* W2  = (const float*)d_in[6];
  const float* b2  = (const float*)d_in[7];
  const float* g2  = (const float*)d_in[8];
  const float* be2 = (const float*)d_in[9];
  const float* W3  = (const float*)d_in[10];
  const float* b3  = (const float*)d_in[11];
  const float* g3  = (const float*)d_in[12];
  const float* be3 = (const float*)d_in[13];
  float* out = (float*)d_out;
  f16* wt = (f16*)d_ws;  // needs 5*128*136*2 = 174080 B of scratch

  const int prep_total = 5 * WBUF_ELEMS;
  prep_weights<<<(prep_total + 255) / 256, 256, 0, stream>>>(W1, W2, W3, wt);
  fused_subgraph<<<PCNT / NPOLY, 256, 0, stream>>>(hs, lens, wt,
                                                   b1, g1, be1, b2, g2, be2, b3, g3, be3,
                                                   out);
}

// Round 8
// 133.984 us; speedup vs baseline: 24.8119x; 24.8119x over previous
//
#include <hip/hip_runtime.h>
#include <stdint.h>

// Problem constants (fixed by the reference): P=8192, L=64, H=128.
#define PCNT 8192
#define LROW 64
#define HDIM 128
#define XSTR 136                    // padded k-stride for x_lds and wt (16B aligned)
#define WBUF_ELEMS (128 * XSTR)     // one transposed weight buffer in ws, fp16

typedef _Float16 f16;
typedef __attribute__((ext_vector_type(8))) _Float16 half8;
typedef __attribute__((ext_vector_type(4))) _Float16 half4v;
typedef __attribute__((ext_vector_type(2))) _Float16 half2v;
typedef __attribute__((ext_vector_type(4))) float f32x4;

#define MFMA16(A, B, C) __builtin_amdgcn_mfma_f32_16x16x32_f16((A), (B), (C), 0, 0, 0)

__device__ __forceinline__ half8 ldh8(const f16* p) {
  return *reinterpret_cast<const half8*>(p);
}

union PkU { uint32_t u; half2v h; };

__device__ __forceinline__ uint32_t pk2(float lo, float hi) {
  PkU a;
  a.h[0] = (f16)lo;
  a.h[1] = (f16)hi;
  return a.u;
}

__device__ __forceinline__ uint32_t pkmax(uint32_t a, uint32_t b) {
  uint32_t d;
  asm("v_pk_max_f16 %0, %1, %2" : "=v"(d) : "v"(a), "v"(b));
  return d;
}

// ---------------------------------------------------------------------------
// Prep: W1 (128x128), W2/W3 (256x128) fp32 row-major  ->  ws as 5 transposed
// fp16 buffers Wt[c][k] with padded stride XSTR:
//   buf0 = W1^T, buf1 = W2[:128]^T (Wa2), buf2 = W2[128:]^T (Wb2),
//   buf3 = W3[:128]^T (Wa3), buf4 = W3[128:]^T (Wb3)
// ---------------------------------------------------------------------------
__global__ void prep_weights(const float* __restrict__ W1,
                             const float* __restrict__ W2,
                             const float* __restrict__ W3,
                             f16* __restrict__ wt) {
  int idx = blockIdx.x * 256 + threadIdx.x;
  if (idx >= 5 * WBUF_ELEMS) return;
  int buf = idx / WBUF_ELEMS;
  int rem = idx - buf * WBUF_ELEMS;
  int c = rem / XSTR;      // output column 0..127
  int k = rem - c * XSTR;  // k index 0..135 (128..135 = pad)
  float v = 0.0f;
  if (k < 128) {
    const float* W = (buf == 0) ? W1 : (buf <= 2 ? W2 : W3);
    int krow = k + ((buf == 2 || buf == 4) ? 128 : 0);
    v = W[krow * 128 + c];
  }
  wt[idx] = (f16)v;
}

// ---------------------------------------------------------------------------
// Fused kernel, transposed-D layout (see R3): 1 block (4 waves) per polyline,
// grid 8192 (NPOLY persistent design abandoned — R6/R7 scratch catastrophe).
// Per layer: wbf+pv seed the accumulators BEFORE the GEMM (R3's 56-VGPR
// spill-free ordering), one stats barrier, per-lane redundant mu/rstd.
// __launch_bounds__(256,6): 6 waves/EU -> 24 waves/CU cap (75%), VGPR budget
// ~85 > the 56 this body needs. ((256,4) capped at 16 waves/CU = R3/R5's 40%;
// (256,8) halved the budget to 64 and spilled — R4.)
// ---------------------------------------------------------------------------
__global__ __launch_bounds__(256, 6)
void fused_subgraph(const float* __restrict__ hs,
                    const int* __restrict__ lens,
                    const f16* __restrict__ wt,
                    const float* __restrict__ b1, const float* __restrict__ g1, const float* __restrict__ be1,
                    const float* __restrict__ b2, const float* __restrict__ g2, const float* __restrict__ be2,
                    const float* __restrict__ b3, const float* __restrict__ g3, const float* __restrict__ be3,
                    float* __restrict__ out) {
  __shared__ __align__(16) f16 x_lds[LROW * XSTR];   // 17408 B
  __shared__ float2 stats_s[4][LROW];                // per-wave row partial (sum, sumsq)
  __shared__ __align__(16) f16 phib[HDIM];           // phi (masked col-max), fp16

  const int tid = threadIdx.x;
  const int w = tid >> 6;   // wave 0..3
  const int l = tid & 63;   // lane
  const int p = blockIdx.x;

  int len = lens[p];
  len = (len < 1) ? 1 : (len > LROW ? LROW : len);
  const int mtiles = (len + 15) >> 4;  // 1..4 M-tiles actually needed

  const int l15 = l & 15;
  const int lg = l >> 4;                    // lane group 0..3
  const int ko = lg * 8;                    // k offset within a 32-k tile
  const int cb0 = w * 32 + lg * 4;          // lane's col base, nt=0 (4 consecutive cols)
  const int cb1 = cb0 + 16;                 // nt=1
  const int wrow0 = (w * 32 + l15) * XSTR;        // weight-fragment row offsets
  const int wrow1 = (w * 32 + 16 + l15) * XSTR;

  // ---- stage input rows [0, 16*mtiles): fp32 -> fp16, b128 LDS writes ----
  {
    const float* hp = hs + (size_t)p * (LROW * HDIM);
    for (int it = 0; it < mtiles; ++it) {
      int e = (it * 256 + tid) * 8;
      int r = e >> 7, c = e & 127;
      float4 va = *reinterpret_cast<const float4*>(hp + e);
      float4 vb = *reinterpret_cast<const float4*>(hp + e + 4);
      half8 hv;
      hv[0] = (f16)va.x; hv[1] = (f16)va.y; hv[2] = (f16)va.z; hv[3] = (f16)va.w;
      hv[4] = (f16)vb.x; hv[5] = (f16)vb.y; hv[6] = (f16)vb.z; hv[7] = (f16)vb.w;
      *reinterpret_cast<half8*>(&x_lds[r * XSTR + c]) = hv;
    }
  }
  __syncthreads();

#pragma unroll
  for (int layer = 0; layer < 3; ++layer) {
    const float* gv  = (layer == 0) ? g1  : (layer == 1) ? g2  : g3;
    const float* bev = (layer == 0) ? be1 : (layer == 1) ? be2 : be3;
    const float* bv  = (layer == 0) ? b1  : (layer == 1) ? b2  : b3;
    const f16* wa = wt + (size_t)((layer == 0) ? 0 : (layer == 1) ? 1 : 3) * WBUF_ELEMS;

    // ---- pv tile: row-constant bias[c] + (phi @ Wb)[c]  (seeds the GEMM acc) ----
    f32x4 pva0, pva1;
    {
      const float4 bl0 = *reinterpret_cast<const float4*>(bv + cb0);
      const float4 bl1 = *reinterpret_cast<const float4*>(bv + cb1);
      pva0[0] = bl0.x; pva0[1] = bl0.y; pva0[2] = bl0.z; pva0[3] = bl0.w;
      pva1[0] = bl1.x; pva1[1] = bl1.y; pva1[2] = bl1.z; pva1[3] = bl1.w;
    }
    if (layer > 0) {
      const f16* wb = wt + (size_t)((layer == 1) ? 2 : 4) * WBUF_ELEMS;
#pragma unroll
      for (int kc = 0; kc < 4; ++kc) {
        half8 wb0 = ldh8(&wb[wrow0 + kc * 32 + ko]);
        half8 wb1 = ldh8(&wb[wrow1 + kc * 32 + ko]);
        half8 ph = ldh8(&phib[kc * 32 + ko]);   // same in all lanes -> row-const D
        pva0 = MFMA16(wb0, ph, pva0);
        pva1 = MFMA16(wb1, ph, pva1);
      }
    }

    // ---- GEMM: acc[mt] = pv + (x @ Wa)^T tile ----
    f32x4 acc[4][2];
#pragma unroll
    for (int mt = 0; mt < 4; ++mt) { acc[mt][0] = pva0; acc[mt][1] = pva1; }
#pragma unroll
    for (int kc = 0; kc < 4; ++kc) {
      half8 wa0 = ldh8(&wa[wrow0 + kc * 32 + ko]);
      half8 wa1 = ldh8(&wa[wrow1 + kc * 32 + ko]);
#pragma unroll
      for (int mt = 0; mt < 4; ++mt) {
        if (mt < mtiles) {
          half8 bx = ldh8(&x_lds[(mt * 16 + l15) * XSTR + kc * 32 + ko]);
          acc[mt][0] = MFMA16(wa0, bx, acc[mt][0]);
          acc[mt][1] = MFMA16(wa1, bx, acc[mt][1]);
        }
      }
    }

    // ---- LN stats: in-lane 8-col partial + xor16/xor32 -> wave partial ----
#pragma unroll
    for (int mt = 0; mt < 4; ++mt) {
      if (mt < mtiles) {
        const f32x4 a0 = acc[mt][0], a1 = acc[mt][1];
        float s = ((a0[0] + a0[1]) + (a0[2] + a0[3])) + ((a1[0] + a1[1]) + (a1[2] + a1[3]));
        float q = a0[0] * a0[0];
        q = fmaf(a0[1], a0[1], q); q = fmaf(a0[2], a0[2], q); q = fmaf(a0[3], a0[3], q);
        q = fmaf(a1[0], a1[0], q); q = fmaf(a1[1], a1[1], q);
        q = fmaf(a1[2], a1[2], q); q = fmaf(a1[3], a1[3], q);
        s += __shfl_xor(s, 16); q += __shfl_xor(q, 16);
        s += __shfl_xor(s, 32); q += __shfl_xor(q, 32);
        if (l < 16) stats_s[w][mt * 16 + l15] = make_float2(s, q);
      }
    }
    __syncthreads();

    // ---- epilogue: per-lane mu/rstd from the 4 wave partials (no barrier),
    //      normalize+relu, write x' (f16), masked packed row-max ----
    const float4 gg0 = *reinterpret_cast<const float4*>(gv + cb0);
    const float4 gg1 = *reinterpret_cast<const float4*>(gv + cb1);
    const float4 eb0 = *reinterpret_cast<const float4*>(bev + cb0);
    const float4 eb1 = *reinterpret_cast<const float4*>(bev + cb1);
    uint32_t pm[4] = {0u, 0u, 0u, 0u};  // packed f16x2 col maxes (relu => 0 is identity)
#pragma unroll
    for (int mt = 0; mt < 4; ++mt) {
      if (mt < mtiles) {
        const int row = mt * 16 + l15;
        float2 t0 = stats_s[0][row], t1 = stats_s[1][row];
        float2 t2 = stats_s[2][row], t3 = stats_s[3][row];
        float s = (t0.x + t1.x) + (t2.x + t3.x);
        float q = (t0.y + t1.y) + (t2.y + t3.y);
        float mu = s * (1.0f / 128.0f);
        float var = q * (1.0f / 128.0f) - mu * mu;
        float rs = rsqrtf(var + 1e-5f);
        const bool valid = row < len;
        float v0 = fmaxf((acc[mt][0][0] - mu) * rs * gg0.x + eb0.x, 0.0f);
        float v1 = fmaxf((acc[mt][0][1] - mu) * rs * gg0.y + eb0.y, 0.0f);
        float v2 = fmaxf((acc[mt][0][2] - mu) * rs * gg0.z + eb0.z, 0.0f);
        float v3 = fmaxf((acc[mt][0][3] - mu) * rs * gg0.w + eb0.w, 0.0f);
        float u0 = fmaxf((acc[mt][1][0] - mu) * rs * gg1.x + eb1.x, 0.0f);
        float u1 = fmaxf((acc[mt][1][1] - mu) * rs * gg1.y + eb1.y, 0.0f);
        float u2 = fmaxf((acc[mt][1][2] - mu) * rs * gg1.z + eb1.z, 0.0f);
        float u3 = fmaxf((acc[mt][1][3] - mu) * rs * gg1.w + eb1.w, 0.0f);
        if (layer < 2) {
          half4v h0; h0[0] = (f16)v0; h0[1] = (f16)v1; h0[2] = (f16)v2; h0[3] = (f16)v3;
          half4v h1; h1[0] = (f16)u0; h1[1] = (f16)u1; h1[2] = (f16)u2; h1[3] = (f16)u3;
          *reinterpret_cast<half4v*>(&x_lds[row * XSTR + cb0]) = h0;
          *reinterpret_cast<half4v*>(&x_lds[row * XSTR + cb1]) = h1;
        }
        pm[0] = pkmax(pm[0], pk2(valid ? v0 : 0.0f, valid ? v1 : 0.0f));
        pm[1] = pkmax(pm[1], pk2(valid ? v2 : 0.0f, valid ? v3 : 0.0f));
        pm[2] = pkmax(pm[2], pk2(valid ? u0 : 0.0f, valid ? u1 : 0.0f));
        pm[3] = pkmax(pm[3], pk2(valid ? u2 : 0.0f, valid ? u3 : 0.0f));
      }
    }
    // reduce over the 16 l15 lanes (rows) — packed f16 max, 4 levels
#pragma unroll
    for (int d = 1; d <= 8; d <<= 1) {
#pragma unroll
      for (int j = 0; j < 4; ++j)
        pm[j] = pkmax(pm[j], (uint32_t)__shfl_xor((int)pm[j], d));
    }

    if (layer < 2) {
      if (l15 == 0) {  // phi for next layer's pv (4 consecutive f16 per uint2)
        *reinterpret_cast<uint2*>(&phib[cb0]) = make_uint2(pm[0], pm[1]);
        *reinterpret_cast<uint2*>(&phib[cb1]) = make_uint2(pm[2], pm[3]);
      }
      __syncthreads();  // x' + phib ready for next layer
    } else {
      if (l15 == 0) {  // output = concat(phi3, phi3)
        PkU q0, q1, q2, q3;
        q0.u = pm[0]; q1.u = pm[1]; q2.u = pm[2]; q3.u = pm[3];
        float4 o0 = make_float4((float)q0.h[0], (float)q0.h[1], (float)q1.h[0], (float)q1.h[1]);
        float4 o1 = make_float4((float)q2.h[0], (float)q2.h[1], (float)q3.h[0], (float)q3.h[1]);
        float* op = out + (size_t)p * 256;
        *reinterpret_cast<float4*>(op + cb0) = o0;
        *reinterpret_cast<float4*>(op + cb1) = o1;
        *reinterpret_cast<float4*>(op + 128 + cb0) = o0;
        *reinterpret_cast<float4*>(op + 128 + cb1) = o1;
      }
    }
  }
}

extern "C" void kernel_launch(void* const* d_in, const int* in_sizes, int n_in,
                              void* d_out, int out_size, void* d_ws, size_t ws_size,
                              hipStream_t stream) {
  const float* hs  = (const float*)d_in[0];
  const int* lens  = (const int*)d_in[1];
  const float* W1  = (const float*)d_in[2];
  const float* b1  = (const float*)d_in[3];
  const float* g1  = (const float*)d_in[4];
  const float* be1 = (const float*)d_in[5];
  const float* W2  = (const float*)d_in[6];
  const float* b2  = (const float*)d_in[7];
  const float* g2  = (const float*)d_in[8];
  const float* be2 = (const float*)d_in[9];
  const float* W3  = (const float*)d_in[10];
  const float* b3  = (const float*)d_in[11];
  const float* g3  = (const float*)d_in[12];
  const float* be3 = (const float*)d_in[13];
  float* out = (float*)d_out;
  f16* wt = (f16*)d_ws;  // needs 5*128*136*2 = 174080 B of scratch

  const int prep_total = 5 * WBUF_ELEMS;
  prep_weights<<<(prep_total + 255) / 256, 256, 0, stream>>>(W1, W2, W3, wt);
  fused_subgraph<<<PCNT, 256, 0, stream>>>(hs, lens, wt,
                                           b1, g1, be1, b2, g2, be2, b3, g3, be3,
                                           out);
}